// Round 1
// 2683.644 us; speedup vs baseline: 5.5439x; 5.5439x over previous
//
#include <hip/hip_runtime.h>
#include <hip/hip_bf16.h>

typedef unsigned short u16;
typedef unsigned int u32;
typedef __attribute__((ext_vector_type(4))) float f32x4;
typedef __attribute__((ext_vector_type(8))) short bf16x8;

// Problem constants (fixed by setup_inputs)
constexpr int BT = 4096, H = 2048, V = 32000;
constexpr long LOGITS_OFF = 1;
constexpr long LSE_OFF    = 1L + (long)BT * V;            // 131072001
constexpr long NTL_OFF    = LSE_OFF + BT;                 // 131076097
constexpr long GX_OFF     = NTL_OFF + BT;                 // 131080193

constexpr int BM = 128, BN = 128, BK = 64;

// ---------- helpers ----------
__device__ __forceinline__ u16 f2bf(float f) {
    u32 u = __float_as_uint(f);
    u = (u + 0x7FFF + ((u >> 16) & 1)) >> 16;   // RNE
    return (u16)u;
}

__device__ __forceinline__ void async_copy16(const void* g, void* l) {
    __builtin_amdgcn_global_load_lds(
        (const __attribute__((address_space(1))) u32*)g,
        (__attribute__((address_space(3))) u32*)l,
        16, 0, 0);
}

// ---------- 1. cast x -> bf16 ----------
__global__ __launch_bounds__(256) void cast_x_kernel(const float* __restrict__ x,
                                                     u16* __restrict__ xb, int n4) {
    int i = blockIdx.x * 256 + threadIdx.x;
    if (i < n4) {
        float4 v = ((const float4*)x)[i];
        union { u16 u[4]; uint2 p; } o;
        o.u[0] = f2bf(v.x); o.u[1] = f2bf(v.y);
        o.u[2] = f2bf(v.z); o.u[3] = f2bf(v.w);
        ((uint2*)xb)[i] = o.p;
    }
}

// ---------- 2. cast + transpose W: W[V][H] fp32 -> wb[V][H] bf16, wt[H][V] bf16 ----------
__global__ __launch_bounds__(256) void wcast_kernel(const float* __restrict__ W,
                                                    u16* __restrict__ wb,
                                                    u16* __restrict__ wt) {
    __shared__ float s[64][65];
    const int h0 = blockIdx.x * 64;      // 32 blocks over H
    const int v0 = blockIdx.y * 64;      // 500 blocks over V
    const int tx = threadIdx.x & 63, ty = threadIdx.x >> 6;   // 64 x 4
#pragma unroll
    for (int i = 0; i < 16; ++i) {
        int v = ty + i * 4;
        float f = W[(long)(v0 + v) * H + h0 + tx];
        s[v][tx] = f;
        wb[(long)(v0 + v) * H + h0 + tx] = f2bf(f);
    }
    __syncthreads();
#pragma unroll
    for (int i = 0; i < 16; ++i) {
        int h = ty + i * 4;
        wt[(long)(h0 + h) * V + v0 + tx] = f2bf(s[tx][h]);
    }
}

// ---------- 3. Generic K-major GEMM: C[M][LDC] = A[M][K] . B[N][K]^T (bf16 in, fp32 out)
//             gemm1: A=xb[BT][H],  B=wb[V][H],  C=logits  (K=H,  LDC=V)
//             gemm2: A=P [BT][V],  B=wt[H][V],  C=gx      (K=V,  LDC=H)
template<int K, int LDC>
__global__ __launch_bounds__(256) void gemm_bt_kernel(const u16* __restrict__ A,
                                                      const u16* __restrict__ B,
                                                      float* __restrict__ C) {
    __shared__ u16 As[BM * BK];
    __shared__ u16 Bs[BN * BK];
    const int tid = threadIdx.x;
    const int n0 = blockIdx.x * BN;
    const int m0 = blockIdx.y * BM;
    const int lane = tid & 63, wave = tid >> 6;
    const int wm = (wave & 1) * 64, wn = (wave >> 1) * 64;
    const int fr = lane & 15, fq = lane >> 4;
    f32x4 acc[4][4] = {};

    for (int k0 = 0; k0 < K; k0 += BK) {
#pragma unroll
        for (int c = 0; c < 4; ++c) {
            int e = c * 2048 + tid * 8;      // flat bf16 elem in 128x64 tile
            int m = e >> 6, k = e & 63;
            async_copy16(&A[(long)(m0 + m) * K + k0 + k], &As[e]);
            async_copy16(&B[(long)(n0 + m) * K + k0 + k], &Bs[e]);
        }
        __syncthreads();   // drains vmcnt for global_load_lds
#pragma unroll
        for (int kk = 0; kk < 2; ++kk) {
            bf16x8 af[4], bfr[4];
#pragma unroll
            for (int i = 0; i < 4; ++i)
                af[i] = *(const bf16x8*)&As[(wm + i * 16 + fr) * BK + kk * 32 + fq * 8];
#pragma unroll
            for (int j = 0; j < 4; ++j)
                bfr[j] = *(const bf16x8*)&Bs[(wn + j * 16 + fr) * BK + kk * 32 + fq * 8];
#pragma unroll
            for (int i = 0; i < 4; ++i)
#pragma unroll
                for (int j = 0; j < 4; ++j)
                    acc[i][j] = __builtin_amdgcn_mfma_f32_16x16x32_bf16(af[i], bfr[j], acc[i][j], 0, 0, 0);
        }
        __syncthreads();
    }
    // epilogue: C/D layout col=lane&15, row=quad*4+reg
#pragma unroll
    for (int i = 0; i < 4; ++i) {
        int cm = m0 + wm + i * 16 + fq * 4;
#pragma unroll
        for (int j = 0; j < 4; ++j) {
            int cn = n0 + wn + j * 16 + fr;
#pragma unroll
            for (int r = 0; r < 4; ++r)
                C[(long)(cm + r) * LDC + cn] = acc[i][j][r];
        }
    }
}

// ---------- 4. per-row logsumexp stats + loss ----------
__global__ __launch_bounds__(256) void stats_kernel(const float* __restrict__ logits,
                                                    const int* __restrict__ target,
                                                    float* __restrict__ loss,
                                                    float* __restrict__ lse_out,
                                                    float* __restrict__ ntl_out) {
    const int row = blockIdx.x;
    const float* p = logits + (long)row * V;
    float m = -1e30f, s = 0.f;
    for (int j = threadIdx.x; j < V; j += 256) {
        float x = p[j];
        float mn = fmaxf(m, x);
        s = s * __expf(m - mn) + __expf(x - mn);
        m = mn;
    }
#pragma unroll
    for (int off = 1; off < 64; off <<= 1) {
        float m2 = __shfl_xor(m, off, 64);
        float s2 = __shfl_xor(s, off, 64);
        float mn = fmaxf(m, m2);
        s = s * __expf(m - mn) + s2 * __expf(m2 - mn);
        m = mn;
    }
    __shared__ float sm[4], ss[4];
    const int wave = threadIdx.x >> 6, lane = threadIdx.x & 63;
    if (lane == 0) { sm[wave] = m; ss[wave] = s; }
    __syncthreads();
    if (threadIdx.x == 0) {
        m = sm[0]; s = ss[0];
#pragma unroll
        for (int w = 1; w < 4; ++w) {
            float mn = fmaxf(m, sm[w]);
            s = s * __expf(m - mn) + ss[w] * __expf(sm[w] - mn);
            m = mn;
        }
        float lse = m + __logf(s);
        float tl = p[target[row]];
        lse_out[row] = lse;
        ntl_out[row] = -tl;
        atomicAdd(loss, (lse - tl) * (1.0f / (float)BT));
    }
}

// ---------- 5. materialize P[BT][V] = exp(logit - lse) as bf16 ----------
// logits is only 4B-aligned (out + 1 float), so scalar dword loads — but
// lane-contiguous per instruction => fully coalesced. Memory-bound pass.
__global__ __launch_bounds__(256) void pcast_kernel(const float* __restrict__ logits,
                                                    const float* __restrict__ lse,
                                                    u16* __restrict__ P) {
    const int row = blockIdx.x;
    const float* p = logits + (long)row * V;
    u16* q = P + (long)row * V;
    const float l = lse[row];
    for (int j = threadIdx.x; j < V; j += 256)
        q[j] = f2bf(__expf(p[j] - l));
}

extern "C" void kernel_launch(void* const* d_in, const int* in_sizes, int n_in,
                              void* d_out, int out_size, void* d_ws, size_t ws_size,
                              hipStream_t stream) {
    const float* x      = (const float*)d_in[0];
    const float* W      = (const float*)d_in[1];
    const int*   target = (const int*)d_in[2];

    float* out    = (float*)d_out;
    float* loss   = out;
    float* logits = out + LOGITS_OFF;
    float* lse    = out + LSE_OFF;
    float* ntl    = out + NTL_OFF;
    float* gx     = out + GX_OFF;

    // Workspace layout (393 MB total):
    //   [0, BT*V)        u16  P   (262 MB)  -- written AFTER gemm1; overlays xb+wb
    //   [BT*V, +V*H)     u16  wt  (131 MB)
    // xb and wb live inside the P region and die when gemm1 completes.
    u16* P  = (u16*)d_ws;                       // [BT][V]
    u16* xb = P;                                // [BT][H]   16.8 MB
    u16* wb = xb + (long)BT * H;                // [V][H]    131 MB  (ends at 148 MB < 262 MB)
    u16* wt = P + (long)BT * V;                 // [H][V]    131 MB

    hipMemsetAsync(loss, 0, sizeof(float), stream);
    cast_x_kernel<<<dim3((BT * H / 4 + 255) / 256), 256, 0, stream>>>(x, xb, BT * H / 4);
    wcast_kernel<<<dim3(H / 64, V / 64), 256, 0, stream>>>(W, wb, wt);
    gemm_bt_kernel<H, V><<<dim3(V / BN, BT / BM), 256, 0, stream>>>(xb, wb, logits);
    stats_kernel<<<dim3(BT), 256, 0, stream>>>(logits, target, loss, lse, ntl);
    pcast_kernel<<<dim3(BT), 256, 0, stream>>>(logits, lse, P);
    gemm_bt_kernel<V, H><<<dim3(H / BN, BT / BM), 256, 0, stream>>>(P, wt, gx);
}